// Round 8
// baseline (282.266 us; speedup 1.0000x reference)
//
#include <hip/hip_runtime.h>
#include <math.h>

#define BB 8
#define CC 512
#define HWN 4096

typedef __bf16 bf16x8 __attribute__((ext_vector_type(8)));
typedef __bf16 bf16x4 __attribute__((ext_vector_type(4)));
typedef float f32x4 __attribute__((ext_vector_type(4)));

#define GLOBAL_AS __attribute__((address_space(1)))
#define LDS_AS __attribute__((address_space(3)))

static __device__ __forceinline__ void async_copy16(const void* g, void* l) {
  __builtin_amdgcn_global_load_lds((const GLOBAL_AS unsigned int*)g,
                                   (LDS_AS unsigned int*)l, 16, 0, 0);
}

// ---------------------------------------------------------------------------
// v9 = v8 skeleton + (a) LDS slot-XOR swizzle, (b) fused-exp epilogue.
//
// (a) Swizzle: [row][32] bf16 rows = 4 16B slots; b128 reads are serviced in
// 16-lane groups, and within lanes 0-15 all even rows hit the same 4-bank
// granule ((row*4+quad)%8 constant) -> 4x over the 2cy floor; measured 3.15M
// conflict-cycles/dispatch. Fix: stored[row][s] = orig[row][s ^ ((row>>1)&3)]
// (XOR involution). global_load_lds dest stays LINEAR; the SOURCE column is
// pre-swizzled (scol = 8*((tid&3)^((tid>>3)&3))) and fragment reads apply the
// same XOR (sq = (quad ^ ((l15>>1)&3))*8) -- rule #21 both-sides-or-neither.
// Global coalescing preserved (permutation within 64B segments only).
//
// (b) EPIMODE 2 (step 1): skip softmax max-subtraction (logits ~ N(0,1));
// write E = exp(v+bias) as bf16 -- B-half rows (m<512) to bmOut (ws),
// V-half rows to Cg (d_out) -- and atomicAdd per-row sums of the fp32 e's
// into rows[batch*1024+m]. Downstream: reduce scales M rows by 1/rowsumB
// (restores exact M incl. the bias-needs-sum(bm)=1 identity), step-6 epilogue
// (EPIMODE 3) scales gdT column i by 1/rowsumV[i] (out = sum_i gd[i,j] *
// E_V[i,hw]/rsv_i). Whole softmax pass (r64MB+w64MB) deleted.
// ---------------------------------------------------------------------------
template <int EPIMODE, typename OUT_T, int NT>
__global__ __launch_bounds__(512, 2) void gemm256_mfma_bt(
    const __bf16* __restrict__ Ag, const __bf16* __restrict__ Bg,
    const float* __restrict__ bias, OUT_T* __restrict__ Cg,
    int M, int N, int K, long sA, long sB, long sC, float alpha,
    int ksl, long sSlice, __bf16* __restrict__ bmOut,
    float* __restrict__ rows) {
  __shared__ __align__(16) __bf16 As[4][256][32];  // 64 KiB
  __shared__ __align__(16) __bf16 Bs[4][256][32];  // 64 KiB

  const int tid = threadIdx.x;
  const int n0 = blockIdx.x * 256;
  const int m0 = blockIdx.y * 256;
  const int bz = blockIdx.z;
  const int batch = bz / ksl;
  const int slice = bz - batch * ksl;
  const int kBeg = slice * (NT * 32);
  Ag += (long)batch * sA;
  Bg += (long)batch * sB;
  Cg += (long)batch * sC + (long)slice * sSlice;
  if (EPIMODE == 2) {
    bmOut += (long)batch * 2097152;  // [512][HWN] per batch
    rows += batch * 1024;
  }

  const int lane = tid & 63;
  const int w = tid >> 6;   // 0..7
  const int wr = w >> 2;    // m-half 0..1
  const int wn = w & 3;     // n-quarter 0..3
  const int l15 = lane & 15, quad = lane >> 4;

  // Swizzled staging source column (16B slot XOR (row>>1)&3; row = tid>>2).
  const int scol = 8 * ((tid & 3) ^ ((tid >> 3) & 3));
  const __bf16* Arow = Ag + (long)(m0 + (tid >> 2)) * K + scol;
  const __bf16* Brow = Bg + (long)(n0 + (tid >> 2)) * K + scol;
  // Swizzled fragment-read slot (row bits 1-2 come from l15 only).
  const int sq = (quad ^ ((l15 >> 1) & 3)) * 8;

  f32x4 acc[8][4] = {};

  auto stageA = [&](int t) {
    const int b = t & 3;  // compile-time after unroll
    const int kk = kBeg + t * 32;
#pragma unroll
    for (int s = 0; s < 2; s++)
      async_copy16(Arow + (long)s * 128 * K + kk,
                   (char*)&As[b][0][0] + s * 8192 + tid * 16);
  };
  auto stageB = [&](int t) {
    const int b = t & 3;
    const int kk = kBeg + t * 32;
#pragma unroll
    for (int s = 0; s < 2; s++)
      async_copy16(Brow + (long)s * 128 * K + kk,
                   (char*)&Bs[b][0][0] + s * 8192 + tid * 16);
  };

  stageA(0); stageB(0);
  stageA(1); stageB(1);
  asm volatile("s_waitcnt vmcnt(4)" ::: "memory");
  __builtin_amdgcn_s_barrier();
  __builtin_amdgcn_sched_barrier(0);

#pragma unroll
  for (int t = 0; t < NT; t++) {
    const int b = t & 3;
    const __bf16(*Asb)[32] = As[b];
    const __bf16(*Bsb)[32] = Bs[b];

    // ---- P0: reads FIRST, then stage issue ----
    bf16x8 bfr[4], af[4];
#pragma unroll
    for (int nj = 0; nj < 4; nj++)
      bfr[nj] = *(const bf16x8*)&Bsb[wn * 64 + nj * 16 + l15][sq];
#pragma unroll
    for (int mi = 0; mi < 4; mi++)
      af[mi] = *(const bf16x8*)&Asb[wr * 128 + mi * 16 + l15][sq];
    __builtin_amdgcn_sched_barrier(0);
    if (t + 2 < NT) stageA(t + 2);
    __builtin_amdgcn_s_barrier();
    __builtin_amdgcn_sched_barrier(0);
    __builtin_amdgcn_s_setprio(1);
#pragma unroll
    for (int mi = 0; mi < 4; mi++)
#pragma unroll
      for (int nj = 0; nj < 4; nj++)
        acc[mi][nj] = __builtin_amdgcn_mfma_f32_16x16x32_bf16(
            af[mi], bfr[nj], acc[mi][nj], 0, 0, 0);
    __builtin_amdgcn_s_setprio(0);
    __builtin_amdgcn_s_barrier();
    __builtin_amdgcn_sched_barrier(0);

    // ---- P1: reads FIRST, stage issue, boundary vmcnt ----
    bf16x8 af2[4];
#pragma unroll
    for (int mi = 0; mi < 4; mi++)
      af2[mi] = *(const bf16x8*)&Asb[wr * 128 + 64 + mi * 16 + l15][sq];
    __builtin_amdgcn_sched_barrier(0);
    if (t + 2 < NT) stageB(t + 2);
    if (t < NT - 2)
      asm volatile("s_waitcnt vmcnt(4)" ::: "memory");
    else
      asm volatile("s_waitcnt vmcnt(0)" ::: "memory");
    __builtin_amdgcn_s_barrier();
    __builtin_amdgcn_sched_barrier(0);
    __builtin_amdgcn_s_setprio(1);
#pragma unroll
    for (int mi = 0; mi < 4; mi++)
#pragma unroll
      for (int nj = 0; nj < 4; nj++)
        acc[mi + 4][nj] = __builtin_amdgcn_mfma_f32_16x16x32_bf16(
            af2[mi], bfr[nj], acc[mi + 4][nj], 0, 0, 0);
    __builtin_amdgcn_s_setprio(0);
    __builtin_amdgcn_s_barrier();
    __builtin_amdgcn_sched_barrier(0);
  }

  if (EPIMODE == 2) {
    // Block-uniform half select (m0 in {0,256} -> B-half, {512,768} -> V).
    __bf16* dstBase = (m0 < 512) ? bmOut : (__bf16*)Cg;
#pragma unroll
    for (int mi = 0; mi < 8; mi++) {
#pragma unroll
      for (int r = 0; r < 4; r++) {
        const int m = m0 + wr * 128 + mi * 16 + quad * 4 + r;
        __bf16* dst = dstBase + (long)m * N;
        float rs = 0.f;
#pragma unroll
        for (int nj = 0; nj < 4; nj++) {
          const int n = n0 + wn * 64 + nj * 16 + l15;
          float v = acc[mi][nj][r] * alpha + bias[m];
          float e = expf(v);  // no max-sub: logits ~N(0,1), fp32-safe
          rs += e;
          dst[n] = (__bf16)e;
        }
        // sum over the 16 l15-lanes (same m, distinct n)
#pragma unroll
        for (int off = 1; off < 16; off <<= 1) rs += __shfl_xor(rs, off, 64);
        if (l15 == 0) atomicAdd(&rows[m], rs);
      }
    }
    return;
  }

#pragma unroll
  for (int mi = 0; mi < 8; mi++) {
#pragma unroll
    for (int nj = 0; nj < 4; nj++) {
#pragma unroll
      for (int r = 0; r < 4; r++) {
        const int m = m0 + wr * 128 + mi * 16 + quad * 4 + r;
        const int n = n0 + wn * 64 + nj * 16 + l15;
        float v = acc[mi][nj][r];
        if (EPIMODE == 1) v += bias[m];
        Cg[(long)m * N + n] = (OUT_T)(v * alpha);
      }
    }
  }
}

// ---------------------------------------------------------------------------
// 128^2 4-wave GEMM — step 6 only. v9: swizzle + EPIMODE 3 epilogue
// (bias, *alpha, then column-scale by 1/rowsumV[n]).
// ---------------------------------------------------------------------------
template <int EPIMODE, typename OUT_T, int NT>
__global__ __launch_bounds__(256) void gemm_mfma_bt(
    const __bf16* __restrict__ Ag, const __bf16* __restrict__ Bg,
    const float* __restrict__ bias, OUT_T* __restrict__ Cg,
    int M, int N, int K, long sA, long sB, long sC, float alpha,
    int ksl, long sSlice, const float* __restrict__ rows) {
  __shared__ __align__(16) __bf16 As[4][128][32];
  __shared__ __align__(16) __bf16 Bs[4][128][32];

  const int tid = threadIdx.x;
  const int n0 = blockIdx.x * 128;
  const int m0 = blockIdx.y * 128;
  const int bz = blockIdx.z;
  const int batch = bz / ksl;
  const int slice = bz - batch * ksl;
  const int kBeg = slice * (NT * 32);
  Ag += (long)batch * sA;
  Bg += (long)batch * sB;
  Cg += (long)batch * sC + (long)slice * sSlice;
  if (EPIMODE == 3) rows += batch * 1024;

  const int lane = tid & 63;
  const int w = tid >> 6;
  const int wr = w >> 1, wc = w & 1;
  const int l15 = lane & 15, quad = lane >> 4;

  const int srow = tid >> 2;
  const int scol = 8 * ((tid & 3) ^ ((tid >> 3) & 3));  // swizzled source
  const __bf16* Arow = Ag + (long)(m0 + srow) * K + scol;
  const __bf16* Brow = Bg + (long)(n0 + srow) * K + scol;
  const int sq = (quad ^ ((l15 >> 1) & 3)) * 8;         // swizzled read

  f32x4 acc[4][4] = {};

  auto stageT = [&](int t) {
    const int b = t & 3;
    const int kk = kBeg + t * 32;
#pragma unroll
    for (int s = 0; s < 2; s++) {
      async_copy16(Arow + (long)s * 64 * K + kk,
                   (char*)&As[b][0][0] + s * 4096 + tid * 16);
      async_copy16(Brow + (long)s * 64 * K + kk,
                   (char*)&Bs[b][0][0] + s * 4096 + tid * 16);
    }
  };

  stageT(0);
  stageT(1);
  stageT(2);

#pragma unroll
  for (int t = 0; t < NT; t++) {
    if (t < NT - 2)
      asm volatile("s_waitcnt vmcnt(8)" ::: "memory");
    else if (t == NT - 2)
      asm volatile("s_waitcnt vmcnt(4)" ::: "memory");
    else
      asm volatile("s_waitcnt vmcnt(0)" ::: "memory");
    __builtin_amdgcn_s_barrier();
    __builtin_amdgcn_sched_barrier(0);

    const int b = t & 3;
    bf16x8 af[4], bfr[4];
#pragma unroll
    for (int u = 0; u < 4; u++) {
      af[u]  = *(const bf16x8*)&As[b][wr * 64 + u * 16 + l15][sq];
      bfr[u] = *(const bf16x8*)&Bs[b][wc * 64 + u * 16 + l15][sq];
    }
    __builtin_amdgcn_sched_barrier(0);
    if (t + 3 < NT) stageT(t + 3);

    __builtin_amdgcn_s_setprio(1);
#pragma unroll
    for (int ti = 0; ti < 4; ti++)
#pragma unroll
      for (int tj = 0; tj < 4; tj++)
        acc[ti][tj] = __builtin_amdgcn_mfma_f32_16x16x32_bf16(
            af[ti], bfr[tj], acc[ti][tj], 0, 0, 0);
    __builtin_amdgcn_s_setprio(0);
  }

  float rinv[4];
  if (EPIMODE == 3) {
#pragma unroll
    for (int tj = 0; tj < 4; tj++) {
      const int n = n0 + wc * 64 + tj * 16 + l15;
      rinv[tj] = 1.0f / rows[512 + n];  // V-rowsums live at [512..1024)
    }
  }

#pragma unroll
  for (int ti = 0; ti < 4; ti++) {
#pragma unroll
    for (int tj = 0; tj < 4; tj++) {
#pragma unroll
      for (int r = 0; r < 4; r++) {
        const int m = m0 + wr * 64 + ti * 16 + quad * 4 + r;
        const int n = n0 + wc * 64 + tj * 16 + l15;
        float v = acc[ti][tj][r];
        if (EPIMODE == 1 || EPIMODE == 3) v += bias[m];
        v *= alpha;
        if (EPIMODE == 3) v *= rinv[tj];
        Cg[(long)m * N + n] = (OUT_T)v;
      }
    }
  }
}

// ---------------------------------------------------------------------------
// Reduce bf16 split-K partials -> Mb, scaling row i by 1/rowsumB[i]
// (restores exact M from unnormalized E_B partial products).
// ---------------------------------------------------------------------------
__global__ __launch_bounds__(256) void reduce_partials8b(
    const __bf16* __restrict__ P, __bf16* __restrict__ out,
    const float* __restrict__ rows) {
  const long i = ((long)blockIdx.x * 256 + threadIdx.x) * 8;  // < 2M
  const int b = (int)(i >> 18);
  const long il = i & 262143;
  const int row = (int)(il >> 9);  // [512][512] per batch
  const float inv = 1.0f / rows[b * 1024 + row];
  const __bf16* p = P + (long)b * 2097152 + il;
  float s[8] = {};
#pragma unroll
  for (int sl = 0; sl < 8; sl++) {
    bf16x8 t = *(const bf16x8*)&p[(long)sl * 262144];
#pragma unroll
    for (int j = 0; j < 8; j++) s[j] += (float)t[j];
  }
  bf16x8 o;
#pragma unroll
  for (int j = 0; j < 8; j++) o[j] = (__bf16)(s[j] * inv);
  *(bf16x8*)&out[i] = o;
}

// ---------------------------------------------------------------------------
// z<8:  x (fp32 [C,HW] batch z) -> xb (bf16) + xT (bf16 [HW,C]).
// z==8: weight/bias conversion + rows[] zeroing.
// ---------------------------------------------------------------------------
__global__ __launch_bounds__(256) void convert_all(
    const float* __restrict__ x, __bf16* __restrict__ xb,
    __bf16* __restrict__ xT, const float* __restrict__ wA,
    const float* __restrict__ wB, const float* __restrict__ wV,
    const float* __restrict__ bB, const float* __restrict__ bV,
    __bf16* __restrict__ wAb, __bf16* __restrict__ wBVb,
    float* __restrict__ bBV, float* __restrict__ rows) {
  if (blockIdx.z == 8) {
    const int t = blockIdx.y * 64 + blockIdx.x;  // 0..511
    const int grp = t >> 7;
    const int r = t & 127;
    if (grp == 3) {
      if (r == 0) {
#pragma unroll
        for (int j = 0; j < 4; j++) {
          const int i = threadIdx.x * 4 + j;
          bBV[i] = (i < 512) ? bB[i] : bV[i - 512];
        }
      } else if (r == 1) {
#pragma unroll
        for (int j = 0; j < 32; j++) rows[j * 256 + threadIdx.x] = 0.f;
      }
      return;
    }
    const float* in = grp == 0 ? wB : (grp == 1 ? wV : wA);
    __bf16* o = grp == 0 ? wBVb : (grp == 1 ? wBVb + 262144 : wAb);
    const long base = (long)r * 2048 + threadIdx.x * 8;
    float4 v0 = *(const float4*)&in[base];
    float4 v1 = *(const float4*)&in[base + 4];
    bf16x8 ob;
    ob[0] = (__bf16)v0.x; ob[1] = (__bf16)v0.y; ob[2] = (__bf16)v0.z;
    ob[3] = (__bf16)v0.w; ob[4] = (__bf16)v1.x; ob[5] = (__bf16)v1.y;
    ob[6] = (__bf16)v1.z; ob[7] = (__bf16)v1.w;
    *(bf16x8*)&o[base] = ob;
    return;
  }

  __shared__ __bf16 t[64][72];
  const int j0 = blockIdx.x * 64;
  const int c0 = blockIdx.y * 64;
  const long bofs = (long)blockIdx.z * CC * HWN;
  const int cl = threadIdx.x & 15;
  const int rw = threadIdx.x >> 4;

#pragma unroll
  for (int p = 0; p < 4; p++) {
    const int i = p * 16 + rw;
    const float4 v =
        *(const float4*)&x[bofs + (long)(c0 + i) * HWN + j0 + cl * 4];
    bf16x4 ob;
    ob[0] = (__bf16)v.x; ob[1] = (__bf16)v.y;
    ob[2] = (__bf16)v.z; ob[3] = (__bf16)v.w;
    *(bf16x4*)&xb[bofs + (long)(c0 + i) * HWN + j0 + cl * 4] = ob;
    t[cl * 4 + 0][i] = ob[0];
    t[cl * 4 + 1][i] = ob[1];
    t[cl * 4 + 2][i] = ob[2];
    t[cl * 4 + 3][i] = ob[3];
  }
  __syncthreads();
#pragma unroll
  for (int p = 0; p < 4; p++) {
    const int jj = p * 16 + rw;
    bf16x4 o;
    o[0] = t[jj][cl * 4 + 0];
    o[1] = t[jj][cl * 4 + 1];
    o[2] = t[jj][cl * 4 + 2];
    o[3] = t[jj][cl * 4 + 3];
    *(bf16x4*)&xT[bofs + (long)(j0 + jj) * CC + c0 + cl * 4] = o;
  }
}

// bf16 transpose: out[b*sOut + j*CC + c] = in[b*sIn + c*ldIn + j]
__global__ __launch_bounds__(256) void transpose_bf16_s(
    const __bf16* __restrict__ in, __bf16* __restrict__ out, int ldIn,
    long sIn, long sOut) {
  __shared__ __bf16 t[64][66];
  const int j0 = blockIdx.x * 64;
  const int c0 = blockIdx.y * 64;
  const int j = threadIdx.x & 63;
  const int g = threadIdx.x >> 6;

#pragma unroll
  for (int r = 0; r < 16; r++) {
    const int i = r * 4 + g;
    t[j][i] = in[(long)blockIdx.z * sIn + (long)(c0 + i) * ldIn + j0 + j];
  }
  __syncthreads();
#pragma unroll
  for (int r = 0; r < 16; r++) {
    const int jj = r * 4 + g;
    out[(long)blockIdx.z * sOut + (long)(j0 + jj) * CC + c0 + j] = t[jj][j];
  }
}

// ---------------------------------------------------------------------------
// Plan (v9 — softmax pass eliminated via exp-folding):
//  0. convert_all: x->xb,xT; weights->bf16; biases packed; rows[] zeroed
//  1. E = exp(wBV·x + bBV)  [gemm256 EPI2]: B-half -> bm (ws), V-half ->
//     d_out; per-row sums atomically -> rows[B*1024]
//  3. transpose E_V -> xT region (unnormalized; 1/rsv folds into step 6)
//  4. M' partials split-K=8 (A=bm=E_B, B=xb)          -> d_out bf16
//  5. reduce (× 1/rowsumB[i])                         -> Mb  (exact M)
//  6. gdT = ((wA·M^T + bA)/HW) × 1/rowsumV[i]  [gemm128 EPI3] -> gdT
//  7. out = gdT·E_V^T        [gemm256 EPI0]           -> d_out fp32
// ---------------------------------------------------------------------------
extern "C" void kernel_launch(void* const* d_in, const int* in_sizes, int n_in,
                              void* d_out, int out_size, void* d_ws,
                              size_t ws_size, hipStream_t stream) {
  const float* x  = (const float*)d_in[0];
  const float* wA = (const float*)d_in[1];
  const float* bA = (const float*)d_in[2];
  const float* wB = (const float*)d_in[3];
  const float* bB = (const float*)d_in[4];
  const float* wV = (const float*)d_in[5];
  const float* bV = (const float*)d_in[6];
  float* out = (float*)d_out;

  const size_t nBCHW = (size_t)BB * CC * HWN;   // 16M
  const size_t nBCC  = (size_t)BB * CC * CC;    // 2M
  __bf16* xb   = (__bf16*)d_ws;          // [B,C,HW]
  __bf16* xT   = xb + nBCHW;             // [B,HW,C]; later E_V^T
  __bf16* bm   = xT + nBCHW;             // [B,C,HW] = E_B
  __bf16* Mb   = bm + nBCHW;             // [B,C,C]
  __bf16* gdT  = Mb + nBCC;              // [B,C,C]
  __bf16* wBVb = gdT + nBCC;             // [1024,512]
  __bf16* wAb  = wBVb + (size_t)1024 * CC;
  float*  bBV  = (float*)(wAb + (size_t)CC * CC);  // [1024]
  float*  rows = bBV + 1024;             // [B*1024] exp row sums

  const long sBC_HW = (long)CC * HWN;    // 2097152
  const long sCC = (long)CC * CC;        // 262144

  convert_all<<<dim3(HWN / 64, CC / 64, BB + 1), 256, 0, stream>>>(
      x, xb, xT, wA, wB, wV, bB, bV, wAb, wBVb, bBV, rows);

  __bf16* logits = (__bf16*)d_out;       // V-half E lives here

  // 1. merged E GEMM (M=1024): exp-epilogue, split dest, rowsum atomics
  gemm256_mfma_bt<2, __bf16, 16>
      <<<dim3(HWN / 256, 1024 / 256, BB), 512, 0, stream>>>(
          wBVb, xT, bBV, logits, 1024, HWN, CC, 0, sBC_HW, (long)1024 * HWN,
          1.0f, 1, 0, bm, rows);
  // 3. E_V^T into xT region (xT dead after step 1)
  transpose_bf16_s<<<dim3(HWN / 64, CC / 64, BB), 256, 0, stream>>>(
      logits + 2097152, xT, HWN, (long)1024 * HWN, (long)HWN * CC);
  // 4. M' split-K=8 partials -> d_out bf16 (overwrites E_V: already copied)
  gemm256_mfma_bt<0, __bf16, 16><<<dim3(CC / 256, CC / 256, BB * 8), 512, 0,
                                   stream>>>(bm, xb, nullptr, (__bf16*)out,
                                             CC, CC, HWN, sBC_HW, sBC_HW,
                                             (long)2097152, 1.0f, 8,
                                             (long)262144, nullptr, nullptr);
  // 5. reduce with 1/rowsumB row scale -> Mb
  reduce_partials8b<<<dim3(1024), 256, 0, stream>>>((const __bf16*)out, Mb,
                                                    rows);
  // 6. gdT = ((wA @ M^T + bA)/HW) / rowsumV[n]
  gemm_mfma_bt<3, __bf16, 16><<<dim3(CC / 128, CC / 128, BB), 256, 0,
                                stream>>>(wAb, Mb, bA, gdT, CC, CC, CC, 0,
                                          sCC, sCC, 1.0f / (float)HWN, 1, 0,
                                          rows);
  // 7. out = gdT @ E_V^T -> d_out fp32
  gemm256_mfma_bt<0, float, 16>
      <<<dim3(HWN / 256, CC / 256, BB), 512, 0, stream>>>(
          gdT, xT, nullptr, out, CC, HWN, CC, sCC, sBC_HW, sBC_HW, 1.0f, 1,
          0, nullptr, nullptr);
}

// Round 9
// 260.269 us; speedup vs baseline: 1.0845x; 1.0845x over previous
//
#include <hip/hip_runtime.h>
#include <math.h>

#define BB 8
#define CC 512
#define HWN 4096

typedef __bf16 bf16x8 __attribute__((ext_vector_type(8)));
typedef __bf16 bf16x4 __attribute__((ext_vector_type(4)));
typedef float f32x4 __attribute__((ext_vector_type(4)));

#define GLOBAL_AS __attribute__((address_space(1)))
#define LDS_AS __attribute__((address_space(3)))

static __device__ __forceinline__ void async_copy16(const void* g, void* l) {
  __builtin_amdgcn_global_load_lds((const GLOBAL_AS unsigned int*)g,
                                   (LDS_AS unsigned int*)l, 16, 0, 0);
}

// ---------------------------------------------------------------------------
// v10 = v9 with the EPI2 epilogue cost fixed (R8 post-mortem: +30us from
// precise expf (~25 VALU ops each) and 524K colliding device atomics).
//   - expf -> __expf (v_mul + v_exp, ~4 ops; err 1e-6 << bf16 quantization)
//   - atomics -> LDS-overlay per-block row-sum partials (non-atomic), folded
//     by a tiny rowsum16 kernel. rpart[16 n0blk][8 batch][1024 rows] fp32.
// Swizzle retained: SQ_LDS_BANK_CONFLICT 3.15M -> 0 (R8, verified); neutral
// timing (conflict cycles were MFMA-hidden) but free.
// Schedule = v8 (reads-first 2-phase, 4 bufs, lead-2, counted vmcnt, full
// unroll, static buffer indices).
// ---------------------------------------------------------------------------
template <int EPIMODE, typename OUT_T, int NT>
__global__ __launch_bounds__(512, 2) void gemm256_mfma_bt(
    const __bf16* __restrict__ Ag, const __bf16* __restrict__ Bg,
    const float* __restrict__ bias, OUT_T* __restrict__ Cg,
    int M, int N, int K, long sA, long sB, long sC, float alpha,
    int ksl, long sSlice, __bf16* __restrict__ bmOut,
    float* __restrict__ rpart) {
  __shared__ __align__(16) __bf16 As[4][256][32];  // 64 KiB
  __shared__ __align__(16) __bf16 Bs[4][256][32];  // 64 KiB

  const int tid = threadIdx.x;
  const int n0 = blockIdx.x * 256;
  const int m0 = blockIdx.y * 256;
  const int bz = blockIdx.z;
  const int batch = bz / ksl;
  const int slice = bz - batch * ksl;
  const int kBeg = slice * (NT * 32);
  Ag += (long)batch * sA;
  Bg += (long)batch * sB;
  Cg += (long)batch * sC + (long)slice * sSlice;
  if (EPIMODE == 2) bmOut += (long)batch * 2097152;  // [512][HWN] per batch

  const int lane = tid & 63;
  const int w = tid >> 6;   // 0..7
  const int wr = w >> 2;    // m-half 0..1
  const int wn = w & 3;     // n-quarter 0..3
  const int l15 = lane & 15, quad = lane >> 4;

  // Swizzled staging source column (16B slot XOR (row>>1)&3; row = tid>>2).
  const int scol = 8 * ((tid & 3) ^ ((tid >> 3) & 3));
  const __bf16* Arow = Ag + (long)(m0 + (tid >> 2)) * K + scol;
  const __bf16* Brow = Bg + (long)(n0 + (tid >> 2)) * K + scol;
  // Swizzled fragment-read slot (row bits 1-2 come from l15 only).
  const int sq = (quad ^ ((l15 >> 1) & 3)) * 8;

  f32x4 acc[8][4] = {};

  auto stageA = [&](int t) {
    const int b = t & 3;  // compile-time after unroll
    const int kk = kBeg + t * 32;
#pragma unroll
    for (int s = 0; s < 2; s++)
      async_copy16(Arow + (long)s * 128 * K + kk,
                   (char*)&As[b][0][0] + s * 8192 + tid * 16);
  };
  auto stageB = [&](int t) {
    const int b = t & 3;
    const int kk = kBeg + t * 32;
#pragma unroll
    for (int s = 0; s < 2; s++)
      async_copy16(Brow + (long)s * 128 * K + kk,
                   (char*)&Bs[b][0][0] + s * 8192 + tid * 16);
  };

  stageA(0); stageB(0);
  stageA(1); stageB(1);
  asm volatile("s_waitcnt vmcnt(4)" ::: "memory");
  __builtin_amdgcn_s_barrier();
  __builtin_amdgcn_sched_barrier(0);

#pragma unroll
  for (int t = 0; t < NT; t++) {
    const int b = t & 3;
    const __bf16(*Asb)[32] = As[b];
    const __bf16(*Bsb)[32] = Bs[b];

    // ---- P0: reads FIRST, then stage issue ----
    bf16x8 bfr[4], af[4];
#pragma unroll
    for (int nj = 0; nj < 4; nj++)
      bfr[nj] = *(const bf16x8*)&Bsb[wn * 64 + nj * 16 + l15][sq];
#pragma unroll
    for (int mi = 0; mi < 4; mi++)
      af[mi] = *(const bf16x8*)&Asb[wr * 128 + mi * 16 + l15][sq];
    __builtin_amdgcn_sched_barrier(0);
    if (t + 2 < NT) stageA(t + 2);
    __builtin_amdgcn_s_barrier();
    __builtin_amdgcn_sched_barrier(0);
    __builtin_amdgcn_s_setprio(1);
#pragma unroll
    for (int mi = 0; mi < 4; mi++)
#pragma unroll
      for (int nj = 0; nj < 4; nj++)
        acc[mi][nj] = __builtin_amdgcn_mfma_f32_16x16x32_bf16(
            af[mi], bfr[nj], acc[mi][nj], 0, 0, 0);
    __builtin_amdgcn_s_setprio(0);
    __builtin_amdgcn_s_barrier();
    __builtin_amdgcn_sched_barrier(0);

    // ---- P1: reads FIRST, stage issue, boundary vmcnt ----
    bf16x8 af2[4];
#pragma unroll
    for (int mi = 0; mi < 4; mi++)
      af2[mi] = *(const bf16x8*)&Asb[wr * 128 + 64 + mi * 16 + l15][sq];
    __builtin_amdgcn_sched_barrier(0);
    if (t + 2 < NT) stageB(t + 2);
    if (t < NT - 2)
      asm volatile("s_waitcnt vmcnt(4)" ::: "memory");
    else
      asm volatile("s_waitcnt vmcnt(0)" ::: "memory");
    __builtin_amdgcn_s_barrier();
    __builtin_amdgcn_sched_barrier(0);
    __builtin_amdgcn_s_setprio(1);
#pragma unroll
    for (int mi = 0; mi < 4; mi++)
#pragma unroll
      for (int nj = 0; nj < 4; nj++)
        acc[mi + 4][nj] = __builtin_amdgcn_mfma_f32_16x16x32_bf16(
            af2[mi], bfr[nj], acc[mi + 4][nj], 0, 0, 0);
    __builtin_amdgcn_s_setprio(0);
    __builtin_amdgcn_s_barrier();
    __builtin_amdgcn_sched_barrier(0);
  }

  if (EPIMODE == 2) {
    // E = __expf(logit + bias); row sums via LDS overlay (As is dead; the
    // final K-loop barrier guarantees all waves are past their LDS reads).
    __bf16* dstBase = (m0 < 512) ? bmOut : (__bf16*)Cg;
    float* lrs = (float*)&As[0][0][0];  // [4 wn][256 mlocal] = 4 KB
#pragma unroll
    for (int mi = 0; mi < 8; mi++) {
#pragma unroll
      for (int r = 0; r < 4; r++) {
        const int ml = wr * 128 + mi * 16 + quad * 4 + r;
        const int m = m0 + ml;
        __bf16* dst = dstBase + (long)m * N;
        const float bm_ = bias[m];
        float rs = 0.f;
#pragma unroll
        for (int nj = 0; nj < 4; nj++) {
          const int n = n0 + wn * 64 + nj * 16 + l15;
          float e = __expf(acc[mi][nj][r] * alpha + bm_);
          rs += e;
          dst[n] = (__bf16)e;
        }
#pragma unroll
        for (int off = 1; off < 16; off <<= 1) rs += __shfl_xor(rs, off, 64);
        if (l15 == 0) lrs[wn * 256 + ml] = rs;
      }
    }
    __syncthreads();
    if (tid < 256) {
      const float s =
          lrs[tid] + lrs[256 + tid] + lrs[512 + tid] + lrs[768 + tid];
      rpart[((long)blockIdx.x * 8 + batch) * 1024 + m0 + tid] = s;
    }
    return;
  }

#pragma unroll
  for (int mi = 0; mi < 8; mi++) {
#pragma unroll
    for (int nj = 0; nj < 4; nj++) {
#pragma unroll
      for (int r = 0; r < 4; r++) {
        const int m = m0 + wr * 128 + mi * 16 + quad * 4 + r;
        const int n = n0 + wn * 64 + nj * 16 + l15;
        float v = acc[mi][nj][r];
        if (EPIMODE == 1) v += bias[m];
        Cg[(long)m * N + n] = (OUT_T)(v * alpha);
      }
    }
  }
}

// ---------------------------------------------------------------------------
// rpart[16][8][1024] -> rows[8][1024] (non-atomic 16-way fold).
// ---------------------------------------------------------------------------
__global__ __launch_bounds__(256) void rowsum16(
    const float* __restrict__ rp, float* __restrict__ rows) {
  const int i = blockIdx.x * 256 + threadIdx.x;  // < 8192 = b*1024 + m
  const int b = i >> 10;
  const int m = i & 1023;
  float s = 0.f;
#pragma unroll
  for (int blk = 0; blk < 16; blk++) s += rp[((long)blk * 8 + b) * 1024 + m];
  rows[i] = s;
}

// ---------------------------------------------------------------------------
// 128^2 4-wave GEMM — step 6 only. Swizzled; EPIMODE 3 epilogue
// (bias, *alpha, then column-scale by 1/rowsumV[n]).
// ---------------------------------------------------------------------------
template <int EPIMODE, typename OUT_T, int NT>
__global__ __launch_bounds__(256) void gemm_mfma_bt(
    const __bf16* __restrict__ Ag, const __bf16* __restrict__ Bg,
    const float* __restrict__ bias, OUT_T* __restrict__ Cg,
    int M, int N, int K, long sA, long sB, long sC, float alpha,
    int ksl, long sSlice, const float* __restrict__ rows) {
  __shared__ __align__(16) __bf16 As[4][128][32];
  __shared__ __align__(16) __bf16 Bs[4][128][32];

  const int tid = threadIdx.x;
  const int n0 = blockIdx.x * 128;
  const int m0 = blockIdx.y * 128;
  const int bz = blockIdx.z;
  const int batch = bz / ksl;
  const int slice = bz - batch * ksl;
  const int kBeg = slice * (NT * 32);
  Ag += (long)batch * sA;
  Bg += (long)batch * sB;
  Cg += (long)batch * sC + (long)slice * sSlice;
  if (EPIMODE == 3) rows += batch * 1024;

  const int lane = tid & 63;
  const int w = tid >> 6;
  const int wr = w >> 1, wc = w & 1;
  const int l15 = lane & 15, quad = lane >> 4;

  const int srow = tid >> 2;
  const int scol = 8 * ((tid & 3) ^ ((tid >> 3) & 3));  // swizzled source
  const __bf16* Arow = Ag + (long)(m0 + srow) * K + scol;
  const __bf16* Brow = Bg + (long)(n0 + srow) * K + scol;
  const int sq = (quad ^ ((l15 >> 1) & 3)) * 8;         // swizzled read

  f32x4 acc[4][4] = {};

  auto stageT = [&](int t) {
    const int b = t & 3;
    const int kk = kBeg + t * 32;
#pragma unroll
    for (int s = 0; s < 2; s++) {
      async_copy16(Arow + (long)s * 64 * K + kk,
                   (char*)&As[b][0][0] + s * 4096 + tid * 16);
      async_copy16(Brow + (long)s * 64 * K + kk,
                   (char*)&Bs[b][0][0] + s * 4096 + tid * 16);
    }
  };

  stageT(0);
  stageT(1);
  stageT(2);

#pragma unroll
  for (int t = 0; t < NT; t++) {
    if (t < NT - 2)
      asm volatile("s_waitcnt vmcnt(8)" ::: "memory");
    else if (t == NT - 2)
      asm volatile("s_waitcnt vmcnt(4)" ::: "memory");
    else
      asm volatile("s_waitcnt vmcnt(0)" ::: "memory");
    __builtin_amdgcn_s_barrier();
    __builtin_amdgcn_sched_barrier(0);

    const int b = t & 3;
    bf16x8 af[4], bfr[4];
#pragma unroll
    for (int u = 0; u < 4; u++) {
      af[u]  = *(const bf16x8*)&As[b][wr * 64 + u * 16 + l15][sq];
      bfr[u] = *(const bf16x8*)&Bs[b][wc * 64 + u * 16 + l15][sq];
    }
    __builtin_amdgcn_sched_barrier(0);
    if (t + 3 < NT) stageT(t + 3);

    __builtin_amdgcn_s_setprio(1);
#pragma unroll
    for (int ti = 0; ti < 4; ti++)
#pragma unroll
      for (int tj = 0; tj < 4; tj++)
        acc[ti][tj] = __builtin_amdgcn_mfma_f32_16x16x32_bf16(
            af[ti], bfr[tj], acc[ti][tj], 0, 0, 0);
    __builtin_amdgcn_s_setprio(0);
  }

  float rinv[4];
  if (EPIMODE == 3) {
#pragma unroll
    for (int tj = 0; tj < 4; tj++) {
      const int n = n0 + wc * 64 + tj * 16 + l15;
      rinv[tj] = 1.0f / rows[512 + n];  // V-rowsums live at [512..1024)
    }
  }

#pragma unroll
  for (int ti = 0; ti < 4; ti++) {
#pragma unroll
    for (int tj = 0; tj < 4; tj++) {
#pragma unroll
      for (int r = 0; r < 4; r++) {
        const int m = m0 + wr * 64 + ti * 16 + quad * 4 + r;
        const int n = n0 + wc * 64 + tj * 16 + l15;
        float v = acc[ti][tj][r];
        if (EPIMODE == 1 || EPIMODE == 3) v += bias[m];
        v *= alpha;
        if (EPIMODE == 3) v *= rinv[tj];
        Cg[(long)m * N + n] = (OUT_T)v;
      }
    }
  }
}

// ---------------------------------------------------------------------------
// Reduce bf16 split-K partials -> Mb, scaling row i by 1/rowsumB[i]
// (restores exact M from unnormalized E_B partial products).
// ---------------------------------------------------------------------------
__global__ __launch_bounds__(256) void reduce_partials8b(
    const __bf16* __restrict__ P, __bf16* __restrict__ out,
    const float* __restrict__ rows) {
  const long i = ((long)blockIdx.x * 256 + threadIdx.x) * 8;  // < 2M
  const int b = (int)(i >> 18);
  const long il = i & 262143;
  const int row = (int)(il >> 9);  // [512][512] per batch
  const float inv = 1.0f / rows[b * 1024 + row];
  const __bf16* p = P + (long)b * 2097152 + il;
  float s[8] = {};
#pragma unroll
  for (int sl = 0; sl < 8; sl++) {
    bf16x8 t = *(const bf16x8*)&p[(long)sl * 262144];
#pragma unroll
    for (int j = 0; j < 8; j++) s[j] += (float)t[j];
  }
  bf16x8 o;
#pragma unroll
  for (int j = 0; j < 8; j++) o[j] = (__bf16)(s[j] * inv);
  *(bf16x8*)&out[i] = o;
}

// ---------------------------------------------------------------------------
// z<8:  x (fp32 [C,HW] batch z) -> xb (bf16) + xT (bf16 [HW,C]).
// z==8: weight/bias conversion.
// ---------------------------------------------------------------------------
__global__ __launch_bounds__(256) void convert_all(
    const float* __restrict__ x, __bf16* __restrict__ xb,
    __bf16* __restrict__ xT, const float* __restrict__ wA,
    const float* __restrict__ wB, const float* __restrict__ wV,
    const float* __restrict__ bB, const float* __restrict__ bV,
    __bf16* __restrict__ wAb, __bf16* __restrict__ wBVb,
    float* __restrict__ bBV) {
  if (blockIdx.z == 8) {
    const int t = blockIdx.y * 64 + blockIdx.x;  // 0..511
    const int grp = t >> 7;
    const int r = t & 127;
    if (grp == 3) {
      if (r == 0) {
#pragma unroll
        for (int j = 0; j < 4; j++) {
          const int i = threadIdx.x * 4 + j;
          bBV[i] = (i < 512) ? bB[i] : bV[i - 512];
        }
      }
      return;
    }
    const float* in = grp == 0 ? wB : (grp == 1 ? wV : wA);
    __bf16* o = grp == 0 ? wBVb : (grp == 1 ? wBVb + 262144 : wAb);
    const long base = (long)r * 2048 + threadIdx.x * 8;
    float4 v0 = *(const float4*)&in[base];
    float4 v1 = *(const float4*)&in[base + 4];
    bf16x8 ob;
    ob[0] = (__bf16)v0.x; ob[1] = (__bf16)v0.y; ob[2] = (__bf16)v0.z;
    ob[3] = (__bf16)v0.w; ob[4] = (__bf16)v1.x; ob[5] = (__bf16)v1.y;
    ob[6] = (__bf16)v1.z; ob[7] = (__bf16)v1.w;
    *(bf16x8*)&o[base] = ob;
    return;
  }

  __shared__ __bf16 t[64][72];
  const int j0 = blockIdx.x * 64;
  const int c0 = blockIdx.y * 64;
  const long bofs = (long)blockIdx.z * CC * HWN;
  const int cl = threadIdx.x & 15;
  const int rw = threadIdx.x >> 4;

#pragma unroll
  for (int p = 0; p < 4; p++) {
    const int i = p * 16 + rw;
    const float4 v =
        *(const float4*)&x[bofs + (long)(c0 + i) * HWN + j0 + cl * 4];
    bf16x4 ob;
    ob[0] = (__bf16)v.x; ob[1] = (__bf16)v.y;
    ob[2] = (__bf16)v.z; ob[3] = (__bf16)v.w;
    *(bf16x4*)&xb[bofs + (long)(c0 + i) * HWN + j0 + cl * 4] = ob;
    t[cl * 4 + 0][i] = ob[0];
    t[cl * 4 + 1][i] = ob[1];
    t[cl * 4 + 2][i] = ob[2];
    t[cl * 4 + 3][i] = ob[3];
  }
  __syncthreads();
#pragma unroll
  for (int p = 0; p < 4; p++) {
    const int jj = p * 16 + rw;
    bf16x4 o;
    o[0] = t[jj][cl * 4 + 0];
    o[1] = t[jj][cl * 4 + 1];
    o[2] = t[jj][cl * 4 + 2];
    o[3] = t[jj][cl * 4 + 3];
    *(bf16x4*)&xT[bofs + (long)(j0 + jj) * CC + c0 + cl * 4] = o;
  }
}

// bf16 transpose: out[b*sOut + j*CC + c] = in[b*sIn + c*ldIn + j]
__global__ __launch_bounds__(256) void transpose_bf16_s(
    const __bf16* __restrict__ in, __bf16* __restrict__ out, int ldIn,
    long sIn, long sOut) {
  __shared__ __bf16 t[64][66];
  const int j0 = blockIdx.x * 64;
  const int c0 = blockIdx.y * 64;
  const int j = threadIdx.x & 63;
  const int g = threadIdx.x >> 6;

#pragma unroll
  for (int r = 0; r < 16; r++) {
    const int i = r * 4 + g;
    t[j][i] = in[(long)blockIdx.z * sIn + (long)(c0 + i) * ldIn + j0 + j];
  }
  __syncthreads();
#pragma unroll
  for (int r = 0; r < 16; r++) {
    const int jj = r * 4 + g;
    out[(long)blockIdx.z * sOut + (long)(j0 + jj) * CC + c0 + j] = t[jj][j];
  }
}

// ---------------------------------------------------------------------------
// Plan (v10):
//  0. convert_all: x->xb,xT; weights->bf16; biases packed
//  1. E = exp(wBV·x + bBV)  [gemm256 EPI2]: B-half -> bm (ws), V-half ->
//     d_out; per-(n0blk,batch) row-sum partials -> rpart (non-atomic)
//  2. rowsum16: rpart -> rows[B*1024]
//  3. transpose E_V -> xT region (unnormalized; 1/rsv folds into step 6)
//  4. M' partials split-K=8 (A=bm=E_B, B=xb)          -> d_out bf16
//  5. reduce (× 1/rowsumB[i])                         -> Mb  (exact M)
//  6. gdT = ((wA·M^T + bA)/HW) × 1/rowsumV[i]  [gemm128 EPI3] -> gdT
//  7. out = gdT·E_V^T        [gemm256 EPI0]           -> d_out fp32
// ---------------------------------------------------------------------------
extern "C" void kernel_launch(void* const* d_in, const int* in_sizes, int n_in,
                              void* d_out, int out_size, void* d_ws,
                              size_t ws_size, hipStream_t stream) {
  const float* x  = (const float*)d_in[0];
  const float* wA = (const float*)d_in[1];
  const float* bA = (const float*)d_in[2];
  const float* wB = (const float*)d_in[3];
  const float* bB = (const float*)d_in[4];
  const float* wV = (const float*)d_in[5];
  const float* bV = (const float*)d_in[6];
  float* out = (float*)d_out;

  const size_t nBCHW = (size_t)BB * CC * HWN;   // 16M
  const size_t nBCC  = (size_t)BB * CC * CC;    // 2M
  __bf16* xb   = (__bf16*)d_ws;          // [B,C,HW]
  __bf16* xT   = xb + nBCHW;             // [B,HW,C]; later E_V^T
  __bf16* bm   = xT + nBCHW;             // [B,C,HW] = E_B
  __bf16* Mb   = bm + nBCHW;             // [B,C,C]
  __bf16* gdT  = Mb + nBCC;              // [B,C,C]
  __bf16* wBVb = gdT + nBCC;             // [1024,512]
  __bf16* wAb  = wBVb + (size_t)1024 * CC;
  float*  bBV  = (float*)(wAb + (size_t)CC * CC);  // [1024]
  float*  rows = bBV + 1024;             // [B*1024] exp row sums
  float*  rpart = rows + 8192;           // [16][8][1024] partials (512 KB)

  const long sBC_HW = (long)CC * HWN;    // 2097152
  const long sCC = (long)CC * CC;        // 262144

  convert_all<<<dim3(HWN / 64, CC / 64, BB + 1), 256, 0, stream>>>(
      x, xb, xT, wA, wB, wV, bB, bV, wAb, wBVb, bBV);

  __bf16* logits = (__bf16*)d_out;       // V-half E lives here

  // 1. merged E GEMM (M=1024): __expf epilogue, split dest, rpart partials
  gemm256_mfma_bt<2, __bf16, 16>
      <<<dim3(HWN / 256, 1024 / 256, BB), 512, 0, stream>>>(
          wBVb, xT, bBV, logits, 1024, HWN, CC, 0, sBC_HW, (long)1024 * HWN,
          1.0f, 1, 0, bm, rpart);
  // 2. fold partials -> rows
  rowsum16<<<dim3(32), 256, 0, stream>>>(rpart, rows);
  // 3. E_V^T into xT region (xT dead after step 1)
  transpose_bf16_s<<<dim3(HWN / 64, CC / 64, BB), 256, 0, stream>>>(
      logits + 2097152, xT, HWN, (long)1024 * HWN, (long)HWN * CC);
  // 4. M' split-K=8 partials -> d_out bf16 (overwrites E_V: already copied)
  gemm256_mfma_bt<0, __bf16, 16><<<dim3(CC / 256, CC / 256, BB * 8), 512, 0,
                                   stream>>>(bm, xb, nullptr, (__bf16*)out,
                                             CC, CC, HWN, sBC_HW, sBC_HW,
                                             (long)2097152, 1.0f, 8,
                                             (long)262144, nullptr, nullptr);
  // 5. reduce with 1/rowsumB row scale -> Mb
  reduce_partials8b<<<dim3(1024), 256, 0, stream>>>((const __bf16*)out, Mb,
                                                    rows);
  // 6. gdT = ((wA @ M^T + bA)/HW) / rowsumV[n]
  gemm_mfma_bt<3, __bf16, 16><<<dim3(CC / 128, CC / 128, BB), 256, 0,
                                stream>>>(wAb, Mb, bA, gdT, CC, CC, CC, 0,
                                          sCC, sCC, 1.0f / (float)HWN, 1, 0,
                                          rows);
  // 7. out = gdT @ E_V^T -> d_out fp32
  gemm256_mfma_bt<0, float, 16>
      <<<dim3(HWN / 256, CC / 256, BB), 512, 0, stream>>>(
          gdT, xT, nullptr, out, CC, HWN, CC, sCC, sBC_HW, sBC_HW, 1.0f, 1,
          0, nullptr, nullptr);
}